// Round 1
// baseline (432.671 us; speedup 1.0000x reference)
//
#include <hip/hip_runtime.h>
#include <stdint.h>

#define N_TOTAL 33554432u          // 8*1*64*256*256 ; norm_term = 2^25
#define N_VEC4  8388608u           // N_TOTAL/4
#define K_SEL   262144u            // MIN_KEPT
#define NBIN_S  4096               // sample hist bins (value bits >> 20)
#define NBIN    32768u             // selection bins (value bits >> 17, 15-bit)
#define NSEG    128                // 128 segments x 256 bins
#define FIXSH   44                 // packed u64: [63:44]=count, [43:0]=sum*2^44
#define FIXMASK ((1ULL << FIXSH) - 1ULL)

// ws layout (bytes)
#define OFF_CTRL   0u
#define OFF_RED    4096u                       // 32768 * 8 = 256 KB
#define OFF_SEGC   (4096u + 262144u)           // 128 * 4
#define OFF_SEGS   (4096u + 262144u + 1024u)   // 128 * 8
#define OFF_COPIES (1u << 20)                  // histogram copies start at 1 MB
#define COPY_BYTES (NBIN * 8u)                 // 256 KB per copy

#define GRID_MAIN   2048u
#define STRIDE_MAIN (GRID_MAIN * 256u)         // 524288 float4/step
#define ITERS_MAIN  (N_VEC4 / STRIDE_MAIN)     // exactly 16
#define CAP_STASH   4096u                      // 16 KB LDS of u32 bit-patterns

struct Ctrl { unsigned tlo; };

__device__ __forceinline__ float loss_of(float p, float t, float w) {
    float d = p - t;
    return w * (d * d) * 0x1p-25f;   // exact /2^25 == reference w*(p-t)^2/norm
}

// ---------------- k_sample: ONE block, 1/1024 sample, LDS-only -------------
__global__ __launch_bounds__(1024) void k_sample(const float4* __restrict__ p,
                                                 const float4* __restrict__ t,
                                                 const float4* __restrict__ w,
                                                 Ctrl* __restrict__ ctrl) {
    __shared__ unsigned hc[NBIN_S];
    __shared__ unsigned seg[256];
    __shared__ unsigned suf[257];
    for (int j = threadIdx.x; j < NBIN_S; j += 1024) hc[j] = 0;
    __syncthreads();
    for (int k = 0; k < 8; ++k) {
        int chunk = k * 4 + ((int)threadIdx.x >> 8);          // 0..31
        int idx = chunk * (int)(N_VEC4 / 32u) + ((int)threadIdx.x & 255);
        float4 pv = p[idx], tv = t[idx], wv = w[idx];
        atomicAdd(&hc[__float_as_uint(loss_of(pv.x, tv.x, wv.x)) >> 20], 1u);
        atomicAdd(&hc[__float_as_uint(loss_of(pv.y, tv.y, wv.y)) >> 20], 1u);
        atomicAdd(&hc[__float_as_uint(loss_of(pv.z, tv.z, wv.z)) >> 20], 1u);
        atomicAdd(&hc[__float_as_uint(loss_of(pv.w, tv.w, wv.w)) >> 20], 1u);
    }
    __syncthreads();
    if (threadIdx.x < 256) {
        unsigned s = 0;
        for (int j = 0; j < 16; ++j) s += hc[threadIdx.x * 16 + j];
        seg[threadIdx.x] = s;
    }
    __syncthreads();
    if (threadIdx.x < 256) suf[threadIdx.x] = seg[threadIdx.x];
    if (threadIdx.x == 0) suf[256] = 0;
    __syncthreads();
    for (int off = 1; off < 256; off <<= 1) {
        unsigned v = 0;
        if (threadIdx.x < 256 && threadIdx.x + off < 256) v = suf[threadIdx.x + off];
        __syncthreads();
        if (threadIdx.x < 256) suf[threadIdx.x] += v;
        __syncthreads();
    }
    const unsigned starget = (2u * K_SEL) >> 10;   // 512
    if (threadIdx.x < 256 && suf[threadIdx.x] >= starget && suf[threadIdx.x + 1] < starget) {
        unsigned cum = suf[threadIdx.x + 1];
        int found = (int)threadIdx.x * 16;
        for (int b = (int)threadIdx.x * 16 + 15; b >= (int)threadIdx.x * 16; --b) {
            cum += hc[b];
            if (cum >= starget) { found = b; break; }
        }
        found -= 3;                 // margin: ~30% lower threshold, covers sample noise
        if (found < 0) found = 0;
        ctrl->tlo = ((unsigned)found) << 20;
    }
}

// ---------------- k_main: pipelined stream, atomics decoupled via LDS ------
// The streaming loop contains ZERO vmem atomics: selected elements are
// appended (ds_atomic on lgkmcnt) to a 16 KB LDS stash and flushed as a
// fire-and-forget global-atomic burst at block end. vmcnt queue holds only
// the 3 prefetched float4 loads -> clean double-buffered pipeline.
__global__ __launch_bounds__(256) void k_main(const float4* __restrict__ p,
                                              const float4* __restrict__ t,
                                              const float4* __restrict__ w,
                                              unsigned long long* __restrict__ hist,
                                              const Ctrl* __restrict__ ctrl,
                                              unsigned copymask) {
    __shared__ unsigned ns;
    __shared__ unsigned stash[CAP_STASH];     // raw float bits of selected losses
    if (threadIdx.x == 0) ns = 0;
    __syncthreads();
    const unsigned tlo = ctrl->tlo;
    unsigned long long* __restrict__ h = hist + (size_t)(blockIdx.x & copymask) * NBIN;

#define PROCESS(PV, TV, WV)                                                          \
    {                                                                                \
        float l0 = loss_of((PV).x, (TV).x, (WV).x);                                  \
        float l1 = loss_of((PV).y, (TV).y, (WV).y);                                  \
        float l2 = loss_of((PV).z, (TV).z, (WV).z);                                  \
        float l3 = loss_of((PV).w, (TV).w, (WV).w);                                  \
        unsigned b0 = __float_as_uint(l0), b1 = __float_as_uint(l1);                 \
        unsigned b2 = __float_as_uint(l2), b3 = __float_as_uint(l3);                 \
        if (b0 >= tlo) {                                                             \
            unsigned pos = atomicAdd(&ns, 1u);                                       \
            if (pos < CAP_STASH) stash[pos] = b0;                                    \
            else atomicAdd(&h[b0 >> 17],                                             \
                           (1ULL << FIXSH) | (unsigned long long)(l0 * 0x1p44f));    \
        }                                                                            \
        if (b1 >= tlo) {                                                             \
            unsigned pos = atomicAdd(&ns, 1u);                                       \
            if (pos < CAP_STASH) stash[pos] = b1;                                    \
            else atomicAdd(&h[b1 >> 17],                                             \
                           (1ULL << FIXSH) | (unsigned long long)(l1 * 0x1p44f));    \
        }                                                                            \
        if (b2 >= tlo) {                                                             \
            unsigned pos = atomicAdd(&ns, 1u);                                       \
            if (pos < CAP_STASH) stash[pos] = b2;                                    \
            else atomicAdd(&h[b2 >> 17],                                             \
                           (1ULL << FIXSH) | (unsigned long long)(l2 * 0x1p44f));    \
        }                                                                            \
        if (b3 >= tlo) {                                                             \
            unsigned pos = atomicAdd(&ns, 1u);                                       \
            if (pos < CAP_STASH) stash[pos] = b3;                                    \
            else atomicAdd(&h[b3 >> 17],                                             \
                           (1ULL << FIXSH) | (unsigned long long)(l3 * 0x1p44f));    \
        }                                                                            \
    }

    unsigned i = blockIdx.x * 256u + threadIdx.x;
    float4 pv = p[i], tv = t[i], wv = w[i];
    #pragma unroll 1
    for (unsigned it = 0; it < ITERS_MAIN - 1u; ++it) {
        unsigned nx = i + STRIDE_MAIN;
        float4 pn = p[nx], tn = t[nx], wn = w[nx];   // prefetch next step
        PROCESS(pv, tv, wv);
        pv = pn; tv = tn; wv = wn; i = nx;
    }
    PROCESS(pv, tv, wv);
#undef PROCESS

    __syncthreads();
    unsigned n = ns < CAP_STASH ? ns : CAP_STASH;
    for (unsigned j = threadIdx.x; j < n; j += 256u) {
        unsigned b = stash[j];
        float l = __uint_as_float(b);
        atomicAdd(&h[b >> 17], (1ULL << FIXSH) | (unsigned long long)(l * 0x1p44f));
    }
}

// ---------------- k_reduce: fold copies, emit per-segment totals -----------
__global__ __launch_bounds__(256) void k_reduce(const unsigned long long* __restrict__ hist,
                                                unsigned long long* __restrict__ red,
                                                unsigned* __restrict__ segc,
                                                unsigned long long* __restrict__ segs,
                                                unsigned ncopies) {
    unsigned bin = blockIdx.x * 256u + threadIdx.x;
    unsigned long long acc = 0;
    for (unsigned c = 0; c < ncopies; ++c) acc += hist[(size_t)c * NBIN + bin];
    red[bin] = acc;
    __shared__ unsigned rc[256];
    __shared__ unsigned long long rs[256];
    rc[threadIdx.x] = (unsigned)(acc >> FIXSH);
    rs[threadIdx.x] = acc & FIXMASK;
    __syncthreads();
    for (int off = 128; off; off >>= 1) {
        if ((int)threadIdx.x < off) {
            rc[threadIdx.x] += rc[threadIdx.x + off];
            rs[threadIdx.x] += rs[threadIdx.x + off];
        }
        __syncthreads();
    }
    if (threadIdx.x == 0) { segc[blockIdx.x] = rc[0]; segs[blockIdx.x] = rs[0]; }
}

// ---------------- k_final: two-level suffix scan -> scalar out -------------
__global__ __launch_bounds__(256) void k_final(const unsigned long long* __restrict__ red,
                                               const unsigned* __restrict__ segc,
                                               const unsigned long long* __restrict__ segs,
                                               float* __restrict__ out) {
    __shared__ unsigned sc[NSEG + 1];
    __shared__ unsigned long long ss[NSEG + 1];
    __shared__ unsigned bc[257];
    __shared__ unsigned long long bs[257];
    __shared__ int s_star;
    unsigned t = threadIdx.x;
    if (t == 0) s_star = 0;
    if (t < NSEG) { sc[t] = segc[t]; ss[t] = segs[t]; }
    if (t == 0) { sc[NSEG] = 0; ss[NSEG] = 0; }
    __syncthreads();
    for (int off = 1; off < NSEG; off <<= 1) {
        unsigned v = 0; unsigned long long vs = 0;
        if (t < NSEG && t + off < NSEG) { v = sc[t + off]; vs = ss[t + off]; }
        __syncthreads();
        if (t < NSEG) { sc[t] += v; ss[t] += vs; }
        __syncthreads();
    }
    if (t < NSEG && sc[t] >= K_SEL && sc[t + 1] < K_SEL) s_star = (int)t;
    __syncthreads();
    int s = s_star;
    unsigned long long pk = red[(size_t)s * 256 + t];
    bc[t] = (unsigned)(pk >> FIXSH);
    bs[t] = pk & FIXMASK;
    if (t == 0) { bc[256] = 0; bs[256] = 0; }
    __syncthreads();
    for (int off = 1; off < 256; off <<= 1) {
        unsigned v = 0; unsigned long long vs = 0;
        if (t + off < 256) { v = bc[t + off]; vs = bs[t + off]; }
        __syncthreads();
        bc[t] += v; bs[t] += vs;
        __syncthreads();
    }
    unsigned above = sc[s + 1];
    if (above + bc[t] >= K_SEL && above + bc[t + 1] < K_SEL) {
        unsigned r = K_SEL - (above + bc[t + 1]);
        unsigned cnt_b = bc[t] - bc[t + 1];
        double sum_b = (double)(bs[t] - bs[t + 1]);
        double S_above = (double)ss[s + 1] + (double)bs[t + 1];
        double total = S_above + (double)r * (sum_b / (double)cnt_b);
        out[0] = (float)(total * 0x1p-44 / (double)K_SEL);
    }
}

extern "C" void kernel_launch(void* const* d_in, const int* in_sizes, int n_in,
                              void* d_out, int out_size, void* d_ws, size_t ws_size,
                              hipStream_t stream) {
    const float4* p = (const float4*)d_in[0];
    const float4* t = (const float4*)d_in[1];
    const float4* w = (const float4*)d_in[2];
    char* ws = (char*)d_ws;
    Ctrl* ctrl = (Ctrl*)(ws + OFF_CTRL);
    unsigned long long* red = (unsigned long long*)(ws + OFF_RED);
    unsigned* segc = (unsigned*)(ws + OFF_SEGC);
    unsigned long long* segs = (unsigned long long*)(ws + OFF_SEGS);
    unsigned long long* copies = (unsigned long long*)(ws + OFF_COPIES);

    unsigned ncopies = 1;
    size_t avail = (ws_size > OFF_COPIES) ? ws_size - OFF_COPIES : (size_t)COPY_BYTES;
    while (ncopies < 32u && (size_t)(ncopies * 2u) * COPY_BYTES <= avail) ncopies <<= 1;

    hipMemsetAsync(copies, 0, (size_t)ncopies * COPY_BYTES, stream);
    k_sample<<<1, 1024, 0, stream>>>(p, t, w, ctrl);
    k_main<<<GRID_MAIN, 256, 0, stream>>>(p, t, w, copies, ctrl, ncopies - 1u);
    k_reduce<<<NSEG, 256, 0, stream>>>(copies, red, segc, segs, ncopies);
    k_final<<<1, 256, 0, stream>>>(red, segc, segs, (float*)d_out);
}

// Round 2
// 418.671 us; speedup vs baseline: 1.0334x; 1.0334x over previous
//
#include <hip/hip_runtime.h>
#include <stdint.h>

#define N_TOTAL 33554432u          // 8*1*64*256*256 ; norm_term = 2^25
#define N_VEC4  8388608u           // N_TOTAL/4
#define K_SEL   262144u            // MIN_KEPT
#define NBIN_S  4096               // sample hist bins (value bits >> 20)
#define NBIN    32768u             // selection bins (value bits >> 17, 15-bit)
#define NSEG    128                // 128 segments x 256 bins
#define FIXSH   44                 // packed u64: [63:44]=count, [43:0]=sum*2^44
#define FIXMASK ((1ULL << FIXSH) - 1ULL)

// ws layout (bytes)
#define OFF_CTRL   0u
#define OFF_RED    4096u                       // 32768 * 8 = 256 KB
#define OFF_SEGC   (4096u + 262144u)           // 128 * 4
#define OFF_SEGS   (4096u + 262144u + 1024u)   // 128 * 8
#define OFF_COPIES (1u << 20)                  // histogram copies start at 1 MB
#define COPY_BYTES (NBIN * 8u)                 // 256 KB per copy

#define GRID_MAIN   2048u
#define STRIDE_MAIN (GRID_MAIN * 256u)         // 524288 float4/step
#define OUTER_MAIN  4u                         // 16 strides, 4 per outer iter
#define WCAP        1024u                      // per-wave stash entries (4 KB)

struct Ctrl { unsigned tlo; };

__device__ __forceinline__ float loss_of(float p, float t, float w) {
    float d = p - t;
    return w * (d * d) * 0x1p-25f;   // exact /2^25 == reference w*(p-t)^2/norm
}

// ---------------- k_sample: ONE block, 1/1024 sample, LDS-only -------------
__global__ __launch_bounds__(1024) void k_sample(const float4* __restrict__ p,
                                                 const float4* __restrict__ t,
                                                 const float4* __restrict__ w,
                                                 Ctrl* __restrict__ ctrl) {
    __shared__ unsigned hc[NBIN_S];
    __shared__ unsigned seg[256];
    __shared__ unsigned suf[257];
    for (int j = threadIdx.x; j < NBIN_S; j += 1024) hc[j] = 0;
    __syncthreads();
    for (int k = 0; k < 8; ++k) {
        int chunk = k * 4 + ((int)threadIdx.x >> 8);          // 0..31
        int idx = chunk * (int)(N_VEC4 / 32u) + ((int)threadIdx.x & 255);
        float4 pv = p[idx], tv = t[idx], wv = w[idx];
        atomicAdd(&hc[__float_as_uint(loss_of(pv.x, tv.x, wv.x)) >> 20], 1u);
        atomicAdd(&hc[__float_as_uint(loss_of(pv.y, tv.y, wv.y)) >> 20], 1u);
        atomicAdd(&hc[__float_as_uint(loss_of(pv.z, tv.z, wv.z)) >> 20], 1u);
        atomicAdd(&hc[__float_as_uint(loss_of(pv.w, tv.w, wv.w)) >> 20], 1u);
    }
    __syncthreads();
    if (threadIdx.x < 256) {
        unsigned s = 0;
        for (int j = 0; j < 16; ++j) s += hc[threadIdx.x * 16 + j];
        seg[threadIdx.x] = s;
    }
    __syncthreads();
    if (threadIdx.x < 256) suf[threadIdx.x] = seg[threadIdx.x];
    if (threadIdx.x == 0) suf[256] = 0;
    __syncthreads();
    for (int off = 1; off < 256; off <<= 1) {
        unsigned v = 0;
        if (threadIdx.x < 256 && threadIdx.x + off < 256) v = suf[threadIdx.x + off];
        __syncthreads();
        if (threadIdx.x < 256) suf[threadIdx.x] += v;
        __syncthreads();
    }
    const unsigned starget = (2u * K_SEL) >> 10;   // 512
    if (threadIdx.x < 256 && suf[threadIdx.x] >= starget && suf[threadIdx.x + 1] < starget) {
        unsigned cum = suf[threadIdx.x + 1];
        int found = (int)threadIdx.x * 16;
        for (int b = (int)threadIdx.x * 16 + 15; b >= (int)threadIdx.x * 16; --b) {
            cum += hc[b];
            if (cum >= starget) { found = b; break; }
        }
        found -= 3;                 // margin: ~30% lower threshold, covers sample noise
        if (found < 0) found = 0;
        ctrl->tlo = ((unsigned)found) << 20;
    }
}

// ---------------- k_main: stream + ballot-compacted per-wave LDS stash -----
// Streaming loop contains: 6 prefetched float4 loads, VALU, ballot/mbcnt
// compaction (pure VALU/SALU), and fire-and-forget exec-masked ds_writes.
// No vmem atomics, no returning LDS atomics, no barriers. Each wave owns a
// private WCAP-entry stash (mean fill ~85) and flushes it as a back-to-back
// global-atomic burst at wave end (no block sync needed).
__global__ __launch_bounds__(256) void k_main(const float4* __restrict__ p,
                                              const float4* __restrict__ t,
                                              const float4* __restrict__ w,
                                              unsigned long long* __restrict__ hist,
                                              const Ctrl* __restrict__ ctrl,
                                              unsigned copymask) {
    __shared__ unsigned stash[4 * WCAP];          // 16 KB, 4 waves x WCAP
    const unsigned tlo = ctrl->tlo;
    unsigned long long* __restrict__ h = hist + (size_t)(blockIdx.x & copymask) * NBIN;
    unsigned* __restrict__ wstash = &stash[(threadIdx.x >> 6) * WCAP];
    unsigned wbase = 0;                           // wave-uniform running count

#define EMIT(L, B)                                                                   \
    {                                                                                \
        bool sel = (B) >= tlo;                                                       \
        unsigned long long msk = __ballot(sel);                                      \
        if (sel) {                                                                   \
            unsigned idx = __builtin_amdgcn_mbcnt_hi(                                \
                (unsigned)(msk >> 32),                                               \
                __builtin_amdgcn_mbcnt_lo((unsigned)msk, 0u));                       \
            unsigned pos = wbase + idx;                                              \
            if (pos < WCAP) wstash[pos] = (B);                                       \
            else atomicAdd(&h[(B) >> 17],                                            \
                           (1ULL << FIXSH) | (unsigned long long)((L) * 0x1p44f));   \
        }                                                                            \
        wbase += (unsigned)__popcll(msk);                                            \
    }

#define PROCESS(PV, TV, WV)                                                          \
    {                                                                                \
        float l0 = loss_of((PV).x, (TV).x, (WV).x);                                  \
        float l1 = loss_of((PV).y, (TV).y, (WV).y);                                  \
        float l2 = loss_of((PV).z, (TV).z, (WV).z);                                  \
        float l3 = loss_of((PV).w, (TV).w, (WV).w);                                  \
        unsigned b0 = __float_as_uint(l0), b1 = __float_as_uint(l1);                 \
        unsigned b2 = __float_as_uint(l2), b3 = __float_as_uint(l3);                 \
        EMIT(l0, b0) EMIT(l1, b1) EMIT(l2, b2) EMIT(l3, b3)                          \
    }

    unsigned i = blockIdx.x * 256u + threadIdx.x;
    #pragma unroll 1
    for (unsigned it = 0; it < OUTER_MAIN; ++it) {
        unsigned i1 = i + STRIDE_MAIN;
        unsigned i2 = i + 2u * STRIDE_MAIN;
        unsigned i3 = i + 3u * STRIDE_MAIN;
        // 6 independent loads in flight for each pair of PROCESS phases
        float4 pa = p[i],  ta = t[i],  wa = w[i];
        float4 pb = p[i1], tb = t[i1], wb = w[i1];
        PROCESS(pa, ta, wa);
        float4 pc = p[i2], tc = t[i2], wc = w[i2];
        PROCESS(pb, tb, wb);
        float4 pd = p[i3], td = t[i3], wd = w[i3];
        PROCESS(pc, tc, wc);
        PROCESS(pd, td, wd);
        i += 4u * STRIDE_MAIN;
    }
#undef PROCESS
#undef EMIT

    // per-wave flush: no barrier needed (stash region is wave-private)
    unsigned n = wbase < WCAP ? wbase : WCAP;
    unsigned lane = threadIdx.x & 63u;
    for (unsigned j = lane; j < n; j += 64u) {
        unsigned b = wstash[j];
        float l = __uint_as_float(b);
        atomicAdd(&h[b >> 17], (1ULL << FIXSH) | (unsigned long long)(l * 0x1p44f));
    }
}

// ---------------- k_reduce: fold copies, emit per-segment totals -----------
__global__ __launch_bounds__(256) void k_reduce(const unsigned long long* __restrict__ hist,
                                                unsigned long long* __restrict__ red,
                                                unsigned* __restrict__ segc,
                                                unsigned long long* __restrict__ segs,
                                                unsigned ncopies) {
    unsigned bin = blockIdx.x * 256u + threadIdx.x;
    unsigned long long acc = 0;
    for (unsigned c = 0; c < ncopies; ++c) acc += hist[(size_t)c * NBIN + bin];
    red[bin] = acc;
    __shared__ unsigned rc[256];
    __shared__ unsigned long long rs[256];
    rc[threadIdx.x] = (unsigned)(acc >> FIXSH);
    rs[threadIdx.x] = acc & FIXMASK;
    __syncthreads();
    for (int off = 128; off; off >>= 1) {
        if ((int)threadIdx.x < off) {
            rc[threadIdx.x] += rc[threadIdx.x + off];
            rs[threadIdx.x] += rs[threadIdx.x + off];
        }
        __syncthreads();
    }
    if (threadIdx.x == 0) { segc[blockIdx.x] = rc[0]; segs[blockIdx.x] = rs[0]; }
}

// ---------------- k_final: two-level suffix scan -> scalar out -------------
__global__ __launch_bounds__(256) void k_final(const unsigned long long* __restrict__ red,
                                               const unsigned* __restrict__ segc,
                                               const unsigned long long* __restrict__ segs,
                                               float* __restrict__ out) {
    __shared__ unsigned sc[NSEG + 1];
    __shared__ unsigned long long ss[NSEG + 1];
    __shared__ unsigned bc[257];
    __shared__ unsigned long long bs[257];
    __shared__ int s_star;
    unsigned t = threadIdx.x;
    if (t == 0) s_star = 0;
    if (t < NSEG) { sc[t] = segc[t]; ss[t] = segs[t]; }
    if (t == 0) { sc[NSEG] = 0; ss[NSEG] = 0; }
    __syncthreads();
    for (int off = 1; off < NSEG; off <<= 1) {
        unsigned v = 0; unsigned long long vs = 0;
        if (t < NSEG && t + off < NSEG) { v = sc[t + off]; vs = ss[t + off]; }
        __syncthreads();
        if (t < NSEG) { sc[t] += v; ss[t] += vs; }
        __syncthreads();
    }
    if (t < NSEG && sc[t] >= K_SEL && sc[t + 1] < K_SEL) s_star = (int)t;
    __syncthreads();
    int s = s_star;
    unsigned long long pk = red[(size_t)s * 256 + t];
    bc[t] = (unsigned)(pk >> FIXSH);
    bs[t] = pk & FIXMASK;
    if (t == 0) { bc[256] = 0; bs[256] = 0; }
    __syncthreads();
    for (int off = 1; off < 256; off <<= 1) {
        unsigned v = 0; unsigned long long vs = 0;
        if (t + off < 256) { v = bc[t + off]; vs = bs[t + off]; }
        __syncthreads();
        bc[t] += v; bs[t] += vs;
        __syncthreads();
    }
    unsigned above = sc[s + 1];
    if (above + bc[t] >= K_SEL && above + bc[t + 1] < K_SEL) {
        unsigned r = K_SEL - (above + bc[t + 1]);
        unsigned cnt_b = bc[t] - bc[t + 1];
        double sum_b = (double)(bs[t] - bs[t + 1]);
        double S_above = (double)ss[s + 1] + (double)bs[t + 1];
        double total = S_above + (double)r * (sum_b / (double)cnt_b);
        out[0] = (float)(total * 0x1p-44 / (double)K_SEL);
    }
}

extern "C" void kernel_launch(void* const* d_in, const int* in_sizes, int n_in,
                              void* d_out, int out_size, void* d_ws, size_t ws_size,
                              hipStream_t stream) {
    const float4* p = (const float4*)d_in[0];
    const float4* t = (const float4*)d_in[1];
    const float4* w = (const float4*)d_in[2];
    char* ws = (char*)d_ws;
    Ctrl* ctrl = (Ctrl*)(ws + OFF_CTRL);
    unsigned long long* red = (unsigned long long*)(ws + OFF_RED);
    unsigned* segc = (unsigned*)(ws + OFF_SEGC);
    unsigned long long* segs = (unsigned long long*)(ws + OFF_SEGS);
    unsigned long long* copies = (unsigned long long*)(ws + OFF_COPIES);

    unsigned ncopies = 1;
    size_t avail = (ws_size > OFF_COPIES) ? ws_size - OFF_COPIES : (size_t)COPY_BYTES;
    while (ncopies < 32u && (size_t)(ncopies * 2u) * COPY_BYTES <= avail) ncopies <<= 1;

    hipMemsetAsync(copies, 0, (size_t)ncopies * COPY_BYTES, stream);
    k_sample<<<1, 1024, 0, stream>>>(p, t, w, ctrl);
    k_main<<<GRID_MAIN, 256, 0, stream>>>(p, t, w, copies, ctrl, ncopies - 1u);
    k_reduce<<<NSEG, 256, 0, stream>>>(copies, red, segc, segs, ncopies);
    k_final<<<1, 256, 0, stream>>>(red, segc, segs, (float*)d_out);
}

// Round 3
// 407.531 us; speedup vs baseline: 1.0617x; 1.0273x over previous
//
#include <hip/hip_runtime.h>
#include <stdint.h>

#define N_TOTAL 33554432u          // 8*1*64*256*256 ; norm_term = 2^25
#define N_VEC4  8388608u           // N_TOTAL/4
#define K_SEL   262144u            // MIN_KEPT
#define NBIN_S  4096               // sample hist bins (value bits >> 20)
#define NBIN    32768u             // selection bins (value bits >> 17, 15-bit)
#define NSEG    128                // 128 segments x 256 bins
#define FIXSH   44                 // packed u64: [63:44]=count, [43:0]=sum*2^44
#define FIXMASK ((1ULL << FIXSH) - 1ULL)

// ws layout (bytes)
#define OFF_CTRL   0u
#define OFF_RED    4096u                       // 32768 * 8 = 256 KB
#define OFF_SEGC   (4096u + 262144u)           // 128 * 4
#define OFF_SEGS   (4096u + 262144u + 1024u)   // 128 * 8
#define OFF_COPIES (1u << 20)                  // histogram copies start at 1 MB
#define OFF_SHIST  (OFF_COPIES - 16384u)       // 4096 * 4 sample hist, memset with copies
#define COPY_BYTES (NBIN * 8u)                 // 256 KB per copy

#define GRID_SAMP   64u                        // sample parallelism: 64 blocks
#define SAMP_RATE_LOG 7                        // 64*1024 float4 = 1/128 of elements

struct Ctrl { unsigned tlo; };

__device__ __forceinline__ float loss_of(float p, float t, float w) {
    float d = p - t;
    return w * (d * d) * 0x1p-25f;   // exact /2^25 == reference w*(p-t)^2/norm
}

// ---------------- k_sample_hist: 64 blocks, 1/128 sample -------------------
// Each block histograms 1024 consecutive float4 (16 KB/array) from an evenly
// spaced window into a private LDS hist, then sparse-merges into the global
// 4096-bin histogram. Replaces the old single-block k_sample whose ~1.2 MB
// single-CU stream was a hidden ~100+ us serial stage.
__global__ __launch_bounds__(1024) void k_sample_hist(const float4* __restrict__ p,
                                                      const float4* __restrict__ t,
                                                      const float4* __restrict__ w,
                                                      unsigned* __restrict__ shist) {
    __shared__ unsigned hc[NBIN_S];
    for (int j = threadIdx.x; j < NBIN_S; j += 1024) hc[j] = 0;
    __syncthreads();
    unsigned idx = blockIdx.x * (N_VEC4 / GRID_SAMP) + threadIdx.x;
    float4 pv = p[idx], tv = t[idx], wv = w[idx];
    atomicAdd(&hc[__float_as_uint(loss_of(pv.x, tv.x, wv.x)) >> 20], 1u);
    atomicAdd(&hc[__float_as_uint(loss_of(pv.y, tv.y, wv.y)) >> 20], 1u);
    atomicAdd(&hc[__float_as_uint(loss_of(pv.z, tv.z, wv.z)) >> 20], 1u);
    atomicAdd(&hc[__float_as_uint(loss_of(pv.w, tv.w, wv.w)) >> 20], 1u);
    __syncthreads();
    for (int j = threadIdx.x; j < NBIN_S; j += 1024) {
        unsigned c = hc[j];
        if (c) atomicAdd(&shist[j], c);        // sparse merge, fire-and-forget
    }
}

// ---------------- k_scan: 1 block, suffix-scan 4096 bins -> threshold ------
__global__ __launch_bounds__(256) void k_scan(const unsigned* __restrict__ shist,
                                              Ctrl* __restrict__ ctrl) {
    __shared__ unsigned hc[NBIN_S];
    __shared__ unsigned seg[256];
    __shared__ unsigned suf[257];
    for (int j = threadIdx.x; j < NBIN_S; j += 256) hc[j] = shist[j];
    __syncthreads();
    if (threadIdx.x < 256) {
        unsigned s = 0;
        for (int j = 0; j < 16; ++j) s += hc[threadIdx.x * 16 + j];
        seg[threadIdx.x] = s;
    }
    __syncthreads();
    suf[threadIdx.x] = seg[threadIdx.x];
    if (threadIdx.x == 0) suf[256] = 0;
    __syncthreads();
    for (int off = 1; off < 256; off <<= 1) {
        unsigned v = 0;
        if (threadIdx.x + off < 256) v = suf[threadIdx.x + off];
        __syncthreads();
        suf[threadIdx.x] += v;
        __syncthreads();
    }
    // target ~2*K at full scale => scale by sample rate 1/128
    const unsigned starget = (2u * K_SEL) >> SAMP_RATE_LOG;   // 4096
    if (suf[threadIdx.x] >= starget && suf[threadIdx.x + 1] < starget) {
        unsigned cum = suf[threadIdx.x + 1];
        int found = (int)threadIdx.x * 16;
        for (int b = (int)threadIdx.x * 16 + 15; b >= (int)threadIdx.x * 16; --b) {
            cum += hc[b];
            if (cum >= starget) { found = b; break; }
        }
        found -= 3;                 // margin: ~30% lower threshold, covers sample noise
        if (found < 0) found = 0;
        ctrl->tlo = ((unsigned)found) << 20;
    }
}

// ---------------- k_main: pure stream + packed histogram atomics -----------
// Round-0 structure verbatim (fastest measured variant): no LDS, no barriers,
// no atomic returns. ~3% of elements issue one u64 global atomic into one of
// `ncopies` histogram replicas.
__global__ __launch_bounds__(256) void k_main(const float4* __restrict__ p,
                                              const float4* __restrict__ t,
                                              const float4* __restrict__ w,
                                              unsigned long long* __restrict__ hist,
                                              const Ctrl* __restrict__ ctrl,
                                              unsigned copymask) {
    const unsigned tlo = ctrl->tlo;
    unsigned long long* h = hist + (size_t)(blockIdx.x & copymask) * NBIN;
    const unsigned stride = gridDim.x * 256u;
    for (unsigned i = blockIdx.x * 256u + threadIdx.x; i < N_VEC4; i += stride) {
        float4 pv = p[i], tv = t[i], wv = w[i];
        float l0 = loss_of(pv.x, tv.x, wv.x);
        float l1 = loss_of(pv.y, tv.y, wv.y);
        float l2 = loss_of(pv.z, tv.z, wv.z);
        float l3 = loss_of(pv.w, tv.w, wv.w);
        unsigned b0 = __float_as_uint(l0), b1 = __float_as_uint(l1);
        unsigned b2 = __float_as_uint(l2), b3 = __float_as_uint(l3);
        if (b0 >= tlo) atomicAdd(&h[b0 >> 17], (1ULL << FIXSH) | (unsigned long long)(l0 * 0x1p44f));
        if (b1 >= tlo) atomicAdd(&h[b1 >> 17], (1ULL << FIXSH) | (unsigned long long)(l1 * 0x1p44f));
        if (b2 >= tlo) atomicAdd(&h[b2 >> 17], (1ULL << FIXSH) | (unsigned long long)(l2 * 0x1p44f));
        if (b3 >= tlo) atomicAdd(&h[b3 >> 17], (1ULL << FIXSH) | (unsigned long long)(l3 * 0x1p44f));
    }
}

// ---------------- k_reduce: fold copies, emit per-segment totals -----------
__global__ __launch_bounds__(256) void k_reduce(const unsigned long long* __restrict__ hist,
                                                unsigned long long* __restrict__ red,
                                                unsigned* __restrict__ segc,
                                                unsigned long long* __restrict__ segs,
                                                unsigned ncopies) {
    unsigned bin = blockIdx.x * 256u + threadIdx.x;
    unsigned long long acc = 0;
    for (unsigned c = 0; c < ncopies; ++c) acc += hist[(size_t)c * NBIN + bin];
    red[bin] = acc;
    __shared__ unsigned rc[256];
    __shared__ unsigned long long rs[256];
    rc[threadIdx.x] = (unsigned)(acc >> FIXSH);      // split fields before segment
    rs[threadIdx.x] = acc & FIXMASK;                 // totals (avoid count overflow)
    __syncthreads();
    for (int off = 128; off; off >>= 1) {
        if ((int)threadIdx.x < off) {
            rc[threadIdx.x] += rc[threadIdx.x + off];
            rs[threadIdx.x] += rs[threadIdx.x + off];
        }
        __syncthreads();
    }
    if (threadIdx.x == 0) { segc[blockIdx.x] = rc[0]; segs[blockIdx.x] = rs[0]; }
}

// ---------------- k_final: two-level suffix scan -> scalar out -------------
__global__ __launch_bounds__(256) void k_final(const unsigned long long* __restrict__ red,
                                               const unsigned* __restrict__ segc,
                                               const unsigned long long* __restrict__ segs,
                                               float* __restrict__ out) {
    __shared__ unsigned sc[NSEG + 1];
    __shared__ unsigned long long ss[NSEG + 1];
    __shared__ unsigned bc[257];
    __shared__ unsigned long long bs[257];
    __shared__ int s_star;
    unsigned t = threadIdx.x;
    if (t == 0) s_star = 0;
    if (t < NSEG) { sc[t] = segc[t]; ss[t] = segs[t]; }
    if (t == 0) { sc[NSEG] = 0; ss[NSEG] = 0; }
    __syncthreads();
    for (int off = 1; off < NSEG; off <<= 1) {
        unsigned v = 0; unsigned long long vs = 0;
        if (t < NSEG && t + off < NSEG) { v = sc[t + off]; vs = ss[t + off]; }
        __syncthreads();
        if (t < NSEG) { sc[t] += v; ss[t] += vs; }
        __syncthreads();
    }
    if (t < NSEG && sc[t] >= K_SEL && sc[t + 1] < K_SEL) s_star = (int)t;
    __syncthreads();
    int s = s_star;
    unsigned long long pk = red[(size_t)s * 256 + t];
    bc[t] = (unsigned)(pk >> FIXSH);
    bs[t] = pk & FIXMASK;
    if (t == 0) { bc[256] = 0; bs[256] = 0; }
    __syncthreads();
    for (int off = 1; off < 256; off <<= 1) {
        unsigned v = 0; unsigned long long vs = 0;
        if (t + off < 256) { v = bc[t + off]; vs = bs[t + off]; }
        __syncthreads();
        bc[t] += v; bs[t] += vs;
        __syncthreads();
    }
    unsigned above = sc[s + 1];
    if (above + bc[t] >= K_SEL && above + bc[t + 1] < K_SEL) {
        unsigned r = K_SEL - (above + bc[t + 1]);
        unsigned cnt_b = bc[t] - bc[t + 1];
        double sum_b = (double)(bs[t] - bs[t + 1]);
        double S_above = (double)ss[s + 1] + (double)bs[t + 1];
        double total = S_above + (double)r * (sum_b / (double)cnt_b);
        out[0] = (float)(total * 0x1p-44 / (double)K_SEL);
    }
}

extern "C" void kernel_launch(void* const* d_in, const int* in_sizes, int n_in,
                              void* d_out, int out_size, void* d_ws, size_t ws_size,
                              hipStream_t stream) {
    const float4* p = (const float4*)d_in[0];
    const float4* t = (const float4*)d_in[1];
    const float4* w = (const float4*)d_in[2];
    char* ws = (char*)d_ws;
    Ctrl* ctrl = (Ctrl*)(ws + OFF_CTRL);
    unsigned long long* red = (unsigned long long*)(ws + OFF_RED);
    unsigned* segc = (unsigned*)(ws + OFF_SEGC);
    unsigned long long* segs = (unsigned long long*)(ws + OFF_SEGS);
    unsigned* shist = (unsigned*)(ws + OFF_SHIST);
    unsigned long long* copies = (unsigned long long*)(ws + OFF_COPIES);

    // histogram replicas: as many power-of-2 copies as ws allows, max 32
    unsigned ncopies = 1;
    size_t avail = (ws_size > OFF_COPIES) ? ws_size - OFF_COPIES : (size_t)COPY_BYTES;
    while (ncopies < 32u && (size_t)(ncopies * 2u) * COPY_BYTES <= avail) ncopies <<= 1;

    // one memset covers sample hist (16 KB) + all histogram copies
    hipMemsetAsync(ws + OFF_SHIST, 0, 16384u + (size_t)ncopies * COPY_BYTES, stream);
    k_sample_hist<<<GRID_SAMP, 1024, 0, stream>>>(p, t, w, shist);
    k_scan<<<1, 256, 0, stream>>>(shist, ctrl);
    k_main<<<2048, 256, 0, stream>>>(p, t, w, copies, ctrl, ncopies - 1u);
    k_reduce<<<NSEG, 256, 0, stream>>>(copies, red, segc, segs, ncopies);
    k_final<<<1, 256, 0, stream>>>(red, segc, segs, (float*)d_out);
}

// Round 4
// 394.020 us; speedup vs baseline: 1.0981x; 1.0343x over previous
//
#include <hip/hip_runtime.h>
#include <stdint.h>

#define N_TOTAL 33554432u          // 8*1*64*256*256 ; norm_term = 2^25
#define N_VEC4  8388608u           // N_TOTAL/4
#define K_SEL   262144u            // MIN_KEPT
#define NBIN_S  4096               // sample hist bins (value bits >> 20)
#define NBIN    32768u             // selection bins (value bits >> 17, 15-bit)
#define NSEG    128                // 128 segments x 256 bins
#define FIXSH   44                 // packed u64: [63:44]=count, [43:0]=sum*2^44
#define FIXMASK ((1ULL << FIXSH) - 1ULL)

// ws layout (bytes)
#define OFF_CTRL   0u
#define OFF_RED    4096u                       // 32768 * 8 = 256 KB
#define OFF_SEGC   (4096u + 262144u)           // 128 * 4
#define OFF_SEGS   (4096u + 262144u + 1024u)   // 128 * 8
#define OFF_COPIES (1u << 20)                  // histogram copies start at 1 MB
#define OFF_SHIST  (OFF_COPIES - 16384u)       // 4096 * 4 sample hist, memset with copies
#define COPY_BYTES (NBIN * 8u)                 // 256 KB per copy

#define GRID_SAMP   64u                        // sample parallelism: 64 blocks
#define SAMP_RATE_LOG 7                        // 64*1024 float4 = 1/128 of elements

struct Ctrl { unsigned tlo; };

__device__ __forceinline__ float loss_of(float p, float t, float w) {
    float d = p - t;
    return w * (d * d) * 0x1p-25f;   // exact /2^25 == reference w*(p-t)^2/norm
}

// ---------------- k_sample_hist: 64 blocks, 1/128 sample -------------------
// Each block histograms 1024 consecutive float4 (16 KB/array) from an evenly
// spaced window into a private LDS hist, then sparse-merges into the global
// 4096-bin histogram.
__global__ __launch_bounds__(1024) void k_sample_hist(const float4* __restrict__ p,
                                                      const float4* __restrict__ t,
                                                      const float4* __restrict__ w,
                                                      unsigned* __restrict__ shist) {
    __shared__ unsigned hc[NBIN_S];
    for (int j = threadIdx.x; j < NBIN_S; j += 1024) hc[j] = 0;
    __syncthreads();
    unsigned idx = blockIdx.x * (N_VEC4 / GRID_SAMP) + threadIdx.x;
    float4 pv = p[idx], tv = t[idx], wv = w[idx];
    atomicAdd(&hc[__float_as_uint(loss_of(pv.x, tv.x, wv.x)) >> 20], 1u);
    atomicAdd(&hc[__float_as_uint(loss_of(pv.y, tv.y, wv.y)) >> 20], 1u);
    atomicAdd(&hc[__float_as_uint(loss_of(pv.z, tv.z, wv.z)) >> 20], 1u);
    atomicAdd(&hc[__float_as_uint(loss_of(pv.w, tv.w, wv.w)) >> 20], 1u);
    __syncthreads();
    for (int j = threadIdx.x; j < NBIN_S; j += 1024) {
        unsigned c = hc[j];
        if (c) atomicAdd(&shist[j], c);        // sparse merge, fire-and-forget
    }
}

// ---------------- k_scan: 1 block, suffix-scan 4096 bins -> threshold ------
// TIGHTENED vs prev: starget 2.0K -> 1.4K, margin -3 sample bins -> -1.
// With 524288 samples (1/128), sigma at target ~1%: selected count lands
// ~1.5-2.0x K (was ~4x K). Halves k_main's global-atomic count. Output is
// unchanged: the K-crossing boundary bin is histogram-determined; all bins
// at/above it remain fully counted for any tlo below them.
__global__ __launch_bounds__(256) void k_scan(const unsigned* __restrict__ shist,
                                              Ctrl* __restrict__ ctrl) {
    __shared__ unsigned hc[NBIN_S];
    __shared__ unsigned seg[256];
    __shared__ unsigned suf[257];
    for (int j = threadIdx.x; j < NBIN_S; j += 256) hc[j] = shist[j];
    __syncthreads();
    if (threadIdx.x < 256) {
        unsigned s = 0;
        for (int j = 0; j < 16; ++j) s += hc[threadIdx.x * 16 + j];
        seg[threadIdx.x] = s;
    }
    __syncthreads();
    suf[threadIdx.x] = seg[threadIdx.x];
    if (threadIdx.x == 0) suf[256] = 0;
    __syncthreads();
    for (int off = 1; off < 256; off <<= 1) {
        unsigned v = 0;
        if (threadIdx.x + off < 256) v = suf[threadIdx.x + off];
        __syncthreads();
        suf[threadIdx.x] += v;
        __syncthreads();
    }
    // target ~1.4*K at full scale => scale by sample rate 1/128
    const unsigned starget = (K_SEL * 7u / 5u) >> SAMP_RATE_LOG;   // 2867
    if (suf[threadIdx.x] >= starget && suf[threadIdx.x + 1] < starget) {
        unsigned cum = suf[threadIdx.x + 1];
        int found = (int)threadIdx.x * 16;
        for (int b = (int)threadIdx.x * 16 + 15; b >= (int)threadIdx.x * 16; --b) {
            cum += hc[b];
            if (cum >= starget) { found = b; break; }
        }
        found -= 1;                 // margin: 1 sample bin (~8 selection bins)
        if (found < 0) found = 0;
        ctrl->tlo = ((unsigned)found) << 20;
    }
}

// ---------------- k_main: pure stream + packed histogram atomics -----------
// Round-0 structure verbatim (fastest measured variant): no LDS, no barriers,
// no atomic returns. ~1.5% of elements issue one u64 global atomic into one
// of `ncopies` histogram replicas.
__global__ __launch_bounds__(256) void k_main(const float4* __restrict__ p,
                                              const float4* __restrict__ t,
                                              const float4* __restrict__ w,
                                              unsigned long long* __restrict__ hist,
                                              const Ctrl* __restrict__ ctrl,
                                              unsigned copymask) {
    const unsigned tlo = ctrl->tlo;
    unsigned long long* h = hist + (size_t)(blockIdx.x & copymask) * NBIN;
    const unsigned stride = gridDim.x * 256u;
    for (unsigned i = blockIdx.x * 256u + threadIdx.x; i < N_VEC4; i += stride) {
        float4 pv = p[i], tv = t[i], wv = w[i];
        float l0 = loss_of(pv.x, tv.x, wv.x);
        float l1 = loss_of(pv.y, tv.y, wv.y);
        float l2 = loss_of(pv.z, tv.z, wv.z);
        float l3 = loss_of(pv.w, tv.w, wv.w);
        unsigned b0 = __float_as_uint(l0), b1 = __float_as_uint(l1);
        unsigned b2 = __float_as_uint(l2), b3 = __float_as_uint(l3);
        if (b0 >= tlo) atomicAdd(&h[b0 >> 17], (1ULL << FIXSH) | (unsigned long long)(l0 * 0x1p44f));
        if (b1 >= tlo) atomicAdd(&h[b1 >> 17], (1ULL << FIXSH) | (unsigned long long)(l1 * 0x1p44f));
        if (b2 >= tlo) atomicAdd(&h[b2 >> 17], (1ULL << FIXSH) | (unsigned long long)(l2 * 0x1p44f));
        if (b3 >= tlo) atomicAdd(&h[b3 >> 17], (1ULL << FIXSH) | (unsigned long long)(l3 * 0x1p44f));
    }
}

// ---------------- k_reduce: fold copies, emit per-segment totals -----------
__global__ __launch_bounds__(256) void k_reduce(const unsigned long long* __restrict__ hist,
                                                unsigned long long* __restrict__ red,
                                                unsigned* __restrict__ segc,
                                                unsigned long long* __restrict__ segs,
                                                unsigned ncopies) {
    unsigned bin = blockIdx.x * 256u + threadIdx.x;
    unsigned long long acc = 0;
    for (unsigned c = 0; c < ncopies; ++c) acc += hist[(size_t)c * NBIN + bin];
    red[bin] = acc;
    __shared__ unsigned rc[256];
    __shared__ unsigned long long rs[256];
    rc[threadIdx.x] = (unsigned)(acc >> FIXSH);      // split fields before segment
    rs[threadIdx.x] = acc & FIXMASK;                 // totals (avoid count overflow)
    __syncthreads();
    for (int off = 128; off; off >>= 1) {
        if ((int)threadIdx.x < off) {
            rc[threadIdx.x] += rc[threadIdx.x + off];
            rs[threadIdx.x] += rs[threadIdx.x + off];
        }
        __syncthreads();
    }
    if (threadIdx.x == 0) { segc[blockIdx.x] = rc[0]; segs[blockIdx.x] = rs[0]; }
}

// ---------------- k_final: two-level suffix scan -> scalar out -------------
__global__ __launch_bounds__(256) void k_final(const unsigned long long* __restrict__ red,
                                               const unsigned* __restrict__ segc,
                                               const unsigned long long* __restrict__ segs,
                                               float* __restrict__ out) {
    __shared__ unsigned sc[NSEG + 1];
    __shared__ unsigned long long ss[NSEG + 1];
    __shared__ unsigned bc[257];
    __shared__ unsigned long long bs[257];
    __shared__ int s_star;
    unsigned t = threadIdx.x;
    if (t == 0) s_star = 0;
    if (t < NSEG) { sc[t] = segc[t]; ss[t] = segs[t]; }
    if (t == 0) { sc[NSEG] = 0; ss[NSEG] = 0; }
    __syncthreads();
    for (int off = 1; off < NSEG; off <<= 1) {
        unsigned v = 0; unsigned long long vs = 0;
        if (t < NSEG && t + off < NSEG) { v = sc[t + off]; vs = ss[t + off]; }
        __syncthreads();
        if (t < NSEG) { sc[t] += v; ss[t] += vs; }
        __syncthreads();
    }
    if (t < NSEG && sc[t] >= K_SEL && sc[t + 1] < K_SEL) s_star = (int)t;
    __syncthreads();
    int s = s_star;
    unsigned long long pk = red[(size_t)s * 256 + t];
    bc[t] = (unsigned)(pk >> FIXSH);
    bs[t] = pk & FIXMASK;
    if (t == 0) { bc[256] = 0; bs[256] = 0; }
    __syncthreads();
    for (int off = 1; off < 256; off <<= 1) {
        unsigned v = 0; unsigned long long vs = 0;
        if (t + off < 256) { v = bc[t + off]; vs = bs[t + off]; }
        __syncthreads();
        bc[t] += v; bs[t] += vs;
        __syncthreads();
    }
    unsigned above = sc[s + 1];
    if (above + bc[t] >= K_SEL && above + bc[t + 1] < K_SEL) {
        unsigned r = K_SEL - (above + bc[t + 1]);
        unsigned cnt_b = bc[t] - bc[t + 1];
        double sum_b = (double)(bs[t] - bs[t + 1]);
        double S_above = (double)ss[s + 1] + (double)bs[t + 1];
        double total = S_above + (double)r * (sum_b / (double)cnt_b);
        out[0] = (float)(total * 0x1p-44 / (double)K_SEL);
    }
}

extern "C" void kernel_launch(void* const* d_in, const int* in_sizes, int n_in,
                              void* d_out, int out_size, void* d_ws, size_t ws_size,
                              hipStream_t stream) {
    const float4* p = (const float4*)d_in[0];
    const float4* t = (const float4*)d_in[1];
    const float4* w = (const float4*)d_in[2];
    char* ws = (char*)d_ws;
    Ctrl* ctrl = (Ctrl*)(ws + OFF_CTRL);
    unsigned long long* red = (unsigned long long*)(ws + OFF_RED);
    unsigned* segc = (unsigned*)(ws + OFF_SEGC);
    unsigned long long* segs = (unsigned long long*)(ws + OFF_SEGS);
    unsigned* shist = (unsigned*)(ws + OFF_SHIST);
    unsigned long long* copies = (unsigned long long*)(ws + OFF_COPIES);

    // histogram replicas: as many power-of-2 copies as ws allows, max 32
    unsigned ncopies = 1;
    size_t avail = (ws_size > OFF_COPIES) ? ws_size - OFF_COPIES : (size_t)COPY_BYTES;
    while (ncopies < 32u && (size_t)(ncopies * 2u) * COPY_BYTES <= avail) ncopies <<= 1;

    // one memset covers sample hist (16 KB) + all histogram copies
    hipMemsetAsync(ws + OFF_SHIST, 0, 16384u + (size_t)ncopies * COPY_BYTES, stream);
    k_sample_hist<<<GRID_SAMP, 1024, 0, stream>>>(p, t, w, shist);
    k_scan<<<1, 256, 0, stream>>>(shist, ctrl);
    k_main<<<2048, 256, 0, stream>>>(p, t, w, copies, ctrl, ncopies - 1u);
    k_reduce<<<NSEG, 256, 0, stream>>>(copies, red, segc, segs, ncopies);
    k_final<<<1, 256, 0, stream>>>(red, segc, segs, (float*)d_out);
}